// Round 1
// baseline (459.494 us; speedup 1.0000x reference)
//
#include <hip/hip_runtime.h>

// ClauseInferModule: C=16 clauses, B=64, G=2048 atoms, S=8 subst, L=4 literals, 3 steps.
// Structure per step:
//   K1 (per clause): p[s] = softand_L(gather(R row)), q = softor_S(p) raw + per-clause max m2
//       - m1 renorm of softand PROVABLY no-op: R <= 1 invariant => softand < 1 strictly.
//       - R[c,b,:] (8 KB) staged in LDS; all gathers become LDS reads.
//   K2 (elementwise): s3 = softor2(R, q/max(m2,1)) + global max m3
//   K3 (elementwise): R = s3 / max(m3,1)
// where(m>1, s/m, s) == s / max(m,1.0f) exactly (division by 1.0 is exact).

namespace {
constexpr int C = 16, B = 64, G = 2048, S = 8, L = 4;
constexpr int STEPS = 3;
constexpr int N  = C * B * G;   // 2,097,152
constexpr int BG = B * G;       // 131,072 (power of two)
}

#define GAMMA 0.001f
#define INVG  1000.0f

// Monotone float->uint key so unsigned atomicMax == float max (handles negatives).
// key(-NaN)=0, so zero-init is the identity element.
__device__ __forceinline__ unsigned f2key(float f) {
    unsigned b = __float_as_uint(f);
    return (b & 0x80000000u) ? ~b : (b | 0x80000000u);
}
__device__ __forceinline__ float key2f(unsigned k) {
    return (k & 0x80000000u) ? __uint_as_float(k & 0x7fffffffu)
                             : __uint_as_float(~k);
}

// ---- K0: R[c,b,g] = x[b,g]; zero the max-key scratch (ws is poisoned 0xAA each call)
__global__ __launch_bounds__(256) void k_init(const float* __restrict__ x,
                                              float* __restrict__ R,
                                              unsigned* __restrict__ mkeys) {
    int idx = blockIdx.x * 256 + threadIdx.x;
    R[idx] = x[idx & (BG - 1)];
    if (idx < 64) mkeys[idx] = 0u;
}

// ---- K1: clause evaluation. grid = C*B*(G/256), block = 256 (one g per thread).
__global__ __launch_bounds__(256) void k_clause(const float* __restrict__ R,
                                                const int* __restrict__ I,
                                                float* __restrict__ q,
                                                unsigned* __restrict__ m2k) {
    __shared__ float lds[G];      // 8 KB: one R row
    __shared__ float wmax[4];

    int blk  = blockIdx.x;
    int tile = blk & (G / 256 - 1);          // 8 tiles per (c,b)
    int cb   = blk >> 3;                     // c*B + b
    int c    = cb >> 6;                      // B = 64

    // stage R[c,b,:] into LDS with float4 (coalesced, 2 per thread)
    const float4* R4 = (const float4*)(R + (size_t)cb * G);
    float4* l4 = (float4*)lds;
    l4[threadIdx.x]       = R4[threadIdx.x];
    l4[threadIdx.x + 256] = R4[threadIdx.x + 256];
    __syncthreads();

    int g = tile * 256 + threadIdx.x;
    const int4* Ibase = (const int4*)(I + (size_t)(c * G + g) * (S * L));

    float p[S];
#pragma unroll
    for (int s = 0; s < S; ++s) {
        int4 ix = Ibase[s];                   // 16 B contiguous per thread
        float v0 = lds[ix.x], v1 = lds[ix.y], v2 = lds[ix.z], v3 = lds[ix.w];
        float vmin = fminf(fminf(v0, v1), fminf(v2, v3));
        float sum = __expf((vmin - v0) * INVG) + __expf((vmin - v1) * INVG)
                  + __expf((vmin - v2) * INVG) + __expf((vmin - v3) * INVG);
        p[s] = vmin - GAMMA * __logf(sum);    // softand (soft-min); renorm no-op (<1)
    }

    float pmax = p[0];
#pragma unroll
    for (int s = 1; s < S; ++s) pmax = fmaxf(pmax, p[s]);
    float sum = 0.0f;
#pragma unroll
    for (int s = 0; s < S; ++s) sum += __expf((p[s] - pmax) * INVG);
    float s2 = pmax + GAMMA * __logf(sum);    // softor over S, pre-renorm

    q[(size_t)cb * G + g] = s2;

    // block max -> one atomic per block into per-clause m2 key
    float m = s2;
    for (int off = 32; off; off >>= 1) m = fmaxf(m, __shfl_down(m, off));
    int lane = threadIdx.x & 63, w = threadIdx.x >> 6;
    if (lane == 0) wmax[w] = m;
    __syncthreads();
    if (threadIdx.x == 0) {
        float mm = fmaxf(fmaxf(wmax[0], wmax[1]), fmaxf(wmax[2], wmax[3]));
        atomicMax(m2k + c, f2key(mm));
    }
}

// ---- K2: s3 = softor2(R, q/max(m2,1)); global max m3. float4, grid = N/4/256.
__global__ __launch_bounds__(256) void k_merge(float* __restrict__ R,
                                               const float* __restrict__ q,
                                               const unsigned* __restrict__ m2k,
                                               unsigned* __restrict__ m3k) {
    __shared__ float wmax[4];
    int idx = blockIdx.x * 256 + threadIdx.x;   // float4 index
    int c = idx >> 15;                          // BG/4 = 32768 float4 per clause
    float m2 = key2f(m2k[c]);
    float den = m2 > 1.0f ? m2 : 1.0f;

    float4 r4 = ((const float4*)R)[idx];
    float4 q4 = ((const float4*)q)[idx];
    float rr[4] = {r4.x, r4.y, r4.z, r4.w};
    float qq[4] = {q4.x, q4.y, q4.z, q4.w};

    float lm = -3.0e38f;
#pragma unroll
    for (int i = 0; i < 4; ++i) {
        float qv = qq[i] / den;
        float hi = fmaxf(rr[i], qv), lo = fminf(rr[i], qv);
        float s3 = hi + GAMMA * __logf(1.0f + __expf((lo - hi) * INVG));
        rr[i] = s3;
        lm = fmaxf(lm, s3);
    }
    ((float4*)R)[idx] = make_float4(rr[0], rr[1], rr[2], rr[3]);

    for (int off = 32; off; off >>= 1) lm = fmaxf(lm, __shfl_down(lm, off));
    int lane = threadIdx.x & 63, w = threadIdx.x >> 6;
    if (lane == 0) wmax[w] = lm;
    __syncthreads();
    if (threadIdx.x == 0) {
        float mm = fmaxf(fmaxf(wmax[0], wmax[1]), fmaxf(wmax[2], wmax[3]));
        atomicMax(m3k, f2key(mm));
    }
}

// ---- K3: R /= max(m3, 1). float4, grid = N/4/256.
__global__ __launch_bounds__(256) void k_scale(float* __restrict__ R,
                                               const unsigned* __restrict__ m3k) {
    float m3 = key2f(*m3k);
    float den = m3 > 1.0f ? m3 : 1.0f;
    int idx = blockIdx.x * 256 + threadIdx.x;
    float4 r = ((float4*)R)[idx];
    r.x /= den; r.y /= den; r.z /= den; r.w /= den;
    ((float4*)R)[idx] = r;
}

extern "C" void kernel_launch(void* const* d_in, const int* in_sizes, int n_in,
                              void* d_out, int out_size, void* d_ws, size_t ws_size,
                              hipStream_t stream) {
    const float* x = (const float*)d_in[0];   // (B, G) fp32
    const int*   I = (const int*)d_in[1];     // (C, G, S, L) int32
    // d_in[2] = infer_step (3) — compile-time STEPS
    float* R = (float*)d_out;                 // (C, B, G) fp32

    float* q = (float*)d_ws;                                          // N floats (8 MB)
    unsigned* mkeys = (unsigned*)((char*)d_ws + (size_t)N * sizeof(float)); // 64 uints

    k_init<<<N / 256, 256, 0, stream>>>(x, R, mkeys);
    for (int step = 0; step < STEPS; ++step) {
        unsigned* m2k = mkeys + step * C;            // 16 per-clause keys
        unsigned* m3k = mkeys + STEPS * C + step;    // 1 global key
        k_clause<<<C * B * (G / 256), 256, 0, stream>>>(R, I, q, m2k);
        k_merge<<<N / 4 / 256, 256, 0, stream>>>(R, q, m2k, m3k);
        k_scale<<<N / 4 / 256, 256, 0, stream>>>(R, m3k);
    }
}

// Round 2
// 245.703 us; speedup vs baseline: 1.8701x; 1.8701x over previous
//
#include <hip/hip_runtime.h>

// ClauseInferModule: C=16, B=64, G=2048, S=8, L=4, 3 steps.
// Per step:
//   k_clause: block=(c, gtile(256), bchunk(8)); I indices register-cached across
//             8 b's; R row staged in double-buffered LDS, pre-divided by
//             den_prev = max(m3_prev, 1). Emits q (raw softor_S of softand_L)
//             and per-clause max m2. softand's renorm is a provable no-op
//             (R <= 1 invariant => softand < 1 strictly).
//   k_merge:  s3 = softor2(R/den_prev, q/max(m2,1)); writes unscaled R_next,
//             accumulates global max m3.
// Final k_scale applies the last m3. where(m>1,s/m,s) == s/max(m,1) exactly.

namespace {
constexpr int C = 16, B = 64, G = 2048, S = 8, L = 4;
constexpr int STEPS = 3;
constexpr int N  = C * B * G;   // 2,097,152
constexpr int BG = B * G;       // 131,072
}

#define GAMMA 0.001f
#define INVG  1000.0f

// Monotone float->uint key: unsigned atomicMax == float max. key(1.0f)=0xBF800000.
__device__ __forceinline__ unsigned f2key(float f) {
    unsigned b = __float_as_uint(f);
    return (b & 0x80000000u) ? ~b : (b | 0x80000000u);
}
__device__ __forceinline__ float key2f(unsigned k) {
    return (k & 0x80000000u) ? __uint_as_float(k & 0x7fffffffu)
                             : __uint_as_float(~k);
}

// mkeys layout: [0..47] m2 (16 per step), [48..50] m3 per step, [51] = key(1.0)
__global__ void k_init(unsigned* __restrict__ mkeys) {
    int t = threadIdx.x;
    if (t < 52) mkeys[t] = (t == 51) ? 0xBF800000u : 0u;
}

// grid = C * 8 * 8 = 1024 blocks, 256 threads.
__global__ __launch_bounds__(256) void k_clause(const float* __restrict__ src, int bcast,
                                                const int* __restrict__ I,
                                                float* __restrict__ q,
                                                unsigned* __restrict__ m2k,
                                                const unsigned* __restrict__ m3prev) {
    __shared__ float lds[2][G];     // 2 x 8 KB double buffer
    __shared__ float wmax[4];

    int blk    = blockIdx.x;
    int bchunk = blk & 7;
    int gtile  = (blk >> 3) & 7;
    int c      = blk >> 6;
    int tid    = threadIdx.x;
    int g      = gtile * 256 + tid;

    // Register-cache this thread's 32 indices (reused for all 8 b's).
    const int4* Ib = (const int4*)(I + (size_t)(c * G + g) * (S * L));
    int4 ix[S];
#pragma unroll
    for (int s = 0; s < S; ++s) ix[s] = Ib[s];

    float denr = 1.0f / fmaxf(key2f(*m3prev), 1.0f);

    // prefetch row b0
    int b0 = bchunk * 8;
    {
        const float4* r4 = (const float4*)(src + (size_t)(bcast ? b0 : (c * B + b0)) * G);
        float4 p0 = r4[tid], p1 = r4[tid + 256];
        lds[0][0] = lds[0][0]; // no-op to keep structure; real write below
        // fallthrough into loop with pre0/pre1 in registers:
        float lmax = -3.0e38f;
        float4 pre0 = p0, pre1 = p1;
        for (int bi = 0; bi < 8; ++bi) {
            int b   = b0 + bi;
            int buf = bi & 1;
            __syncthreads();   // prior reads of lds[buf] (iter bi-2) done
            float4* l4 = (float4*)lds[buf];
            float4 a0 = pre0, a1 = pre1;
            a0.x *= denr; a0.y *= denr; a0.z *= denr; a0.w *= denr;
            a1.x *= denr; a1.y *= denr; a1.z *= denr; a1.w *= denr;
            l4[tid]       = a0;
            l4[tid + 256] = a1;
            if (bi < 7) {   // prefetch next row while this one is consumed
                const float4* rn = (const float4*)(src + (size_t)(bcast ? (b + 1) : (c * B + b + 1)) * G);
                pre0 = rn[tid]; pre1 = rn[tid + 256];
            }
            __syncthreads();   // staging visible

            const float* row = lds[buf];
            float p[S];
#pragma unroll
            for (int s = 0; s < S; ++s) {
                int4 iv = ix[s];
                float v0 = row[iv.x], v1 = row[iv.y], v2 = row[iv.z], v3 = row[iv.w];
                float vmin = fminf(fminf(v0, v1), fminf(v2, v3));
                float sum = __expf((vmin - v0) * INVG) + __expf((vmin - v1) * INVG)
                          + __expf((vmin - v2) * INVG) + __expf((vmin - v3) * INVG);
                p[s] = vmin - GAMMA * __logf(sum);   // softand; renorm no-op (<1)
            }
            float pm = p[0];
#pragma unroll
            for (int s = 1; s < S; ++s) pm = fmaxf(pm, p[s]);
            float sum2 = 0.0f;
#pragma unroll
            for (int s = 0; s < S; ++s) sum2 += __expf((p[s] - pm) * INVG);
            float s2 = pm + GAMMA * __logf(sum2);    // softor over S, pre-renorm

            q[(size_t)(c * B + b) * G + g] = s2;
            lmax = fmaxf(lmax, s2);
        }

        // block-max -> one atomic per block
        float m = lmax;
        for (int off = 32; off; off >>= 1) m = fmaxf(m, __shfl_down(m, off));
        int lane = tid & 63, w = tid >> 6;
        if (lane == 0) wmax[w] = m;
        __syncthreads();
        if (tid == 0) {
            float mm = fmaxf(fmaxf(wmax[0], wmax[1]), fmaxf(wmax[2], wmax[3]));
            atomicMax(m2k + c, f2key(mm));
        }
    }
}

// s3 = softor2(R/den_prev, q/max(m2,1)); write unscaled R_next; global max m3.
__global__ __launch_bounds__(256) void k_merge(const float* __restrict__ src, int bcast,
                                               float* __restrict__ R,
                                               const float* __restrict__ q,
                                               const unsigned* __restrict__ m2k,
                                               const unsigned* __restrict__ m3prev,
                                               unsigned* __restrict__ m3out) {
    __shared__ float wmax[4];
    int idx = blockIdx.x * 256 + threadIdx.x;       // float4 index, N/4 total
    int c   = idx >> 15;                            // BG/4 = 32768 float4 per clause
    float denr = 1.0f / fmaxf(key2f(*m3prev), 1.0f);
    float m2   = key2f(m2k[c]);
    float qden = 1.0f / fmaxf(m2, 1.0f);

    int ridx = bcast ? (idx & (BG / 4 - 1)) : idx;
    float4 r4 = ((const float4*)src)[ridx];
    float4 q4 = ((const float4*)q)[idx];
    float rr[4] = {r4.x, r4.y, r4.z, r4.w};
    float qq[4] = {q4.x, q4.y, q4.z, q4.w};

    float lm = -3.0e38f;
#pragma unroll
    for (int i = 0; i < 4; ++i) {
        float rv = rr[i] * denr;
        float qv = qq[i] * qden;
        float hi = fmaxf(rv, qv), lo = fminf(rv, qv);
        float s3 = hi + GAMMA * __logf(1.0f + __expf((lo - hi) * INVG));
        rr[i] = s3;
        lm = fmaxf(lm, s3);
    }
    ((float4*)R)[idx] = make_float4(rr[0], rr[1], rr[2], rr[3]);

    for (int off = 32; off; off >>= 1) lm = fmaxf(lm, __shfl_down(lm, off));
    int lane = threadIdx.x & 63, w = threadIdx.x >> 6;
    if (lane == 0) wmax[w] = lm;
    __syncthreads();
    if (threadIdx.x == 0) {
        float mm = fmaxf(fmaxf(wmax[0], wmax[1]), fmaxf(wmax[2], wmax[3]));
        atomicMax(m3out, f2key(mm));
    }
}

__global__ __launch_bounds__(256) void k_scale(float* __restrict__ R,
                                               const unsigned* __restrict__ m3k) {
    float denr = 1.0f / fmaxf(key2f(*m3k), 1.0f);
    int idx = blockIdx.x * 256 + threadIdx.x;
    float4 r = ((float4*)R)[idx];
    r.x *= denr; r.y *= denr; r.z *= denr; r.w *= denr;
    ((float4*)R)[idx] = r;
}

extern "C" void kernel_launch(void* const* d_in, const int* in_sizes, int n_in,
                              void* d_out, int out_size, void* d_ws, size_t ws_size,
                              hipStream_t stream) {
    const float* x = (const float*)d_in[0];   // (B, G) fp32
    const int*   I = (const int*)d_in[1];     // (C, G, S, L) int32
    float* R = (float*)d_out;                 // (C, B, G) fp32

    float* q = (float*)d_ws;                                               // N floats
    unsigned* mkeys = (unsigned*)((char*)d_ws + (size_t)N * sizeof(float)); // 52 uints

    k_init<<<1, 64, 0, stream>>>(mkeys);
    for (int step = 0; step < STEPS; ++step) {
        unsigned* m2k    = mkeys + step * C;
        unsigned* m3out  = mkeys + 48 + step;
        const unsigned* m3prev = (step == 0) ? (mkeys + 51) : (mkeys + 48 + step - 1);
        const float* src = (step == 0) ? x : R;
        int bcast = (step == 0) ? 1 : 0;
        k_clause<<<C * 8 * 8, 256, 0, stream>>>(src, bcast, I, q, m2k, m3prev);
        k_merge<<<N / 4 / 256, 256, 0, stream>>>(src, bcast, R, q, m2k, m3prev, m3out);
    }
    k_scale<<<N / 4 / 256, 256, 0, stream>>>(R, mkeys + 48 + STEPS - 1);
}